// Round 1
// 282.034 us; speedup vs baseline: 1.0976x; 1.0976x over previous
//
#include <hip/hip_runtime.h>
#include <stdint.h>

#define D_DIM 128
#define NROW 8192
#define MROW 8192
#define TILE 128
#define OUT_LD 8192
#define NTILE 64   // 8192 / 128 tiles per matrix

typedef __bf16 bf16x8 __attribute__((ext_vector_type(8)));
typedef float f32x4 __attribute__((ext_vector_type(4)));
typedef unsigned short u16x8 __attribute__((ext_vector_type(8)));

__device__ __forceinline__ unsigned short f32_to_bf16(float f) {
    uint32_t u = __float_as_uint(f);
    u = (u + 0x7FFFu + ((u >> 16) & 1u)) >> 16;   // round-to-nearest-even
    return (unsigned short)u;
}

// Exact f32 row norms: one wave per row, X rows then Y rows, into d_ws.
__global__ __launch_bounds__(256) void rbf_norms(const float* __restrict__ X,
                                                 const float* __restrict__ Y,
                                                 float* __restrict__ nrm) {
    const int t = threadIdx.x;
    const int w = t >> 6, lane = t & 63;
    const int rid = blockIdx.x * 4 + w;
    const float* src = (rid < NROW) ? (X + (size_t)rid * D_DIM)
                                    : (Y + (size_t)(rid - NROW) * D_DIM);
    float2 v = *(const float2*)(src + 2 * lane);
    float s = v.x * v.x + v.y * v.y;
    #pragma unroll
    for (int off = 32; off > 0; off >>= 1) s += __shfl_xor(s, off, 64);
    if (lane == 0) nrm[rid] = s;
}

// Pre-convert X,Y -> bf16 in main-kernel-ready chunks.
// Chunk (tile t, phase p) = 16384 B = the exact LDS image for that phase:
//   LDS byte b holds element (row r = b>>7, k2 = (b&127) ^ ((r&7)<<4)).
// The XOR swizzle is baked into the GLOBAL layout so the main kernel can use
// linear global_load_lds (wave-uniform dest + lane*16) and swizzled ds_read.
__global__ __launch_bounds__(256) void rbf_pack(const float* __restrict__ X,
                                                const float* __restrict__ Y,
                                                unsigned short* __restrict__ Xt,
                                                unsigned short* __restrict__ Yt) {
    const int gid = blockIdx.x * 256 + threadIdx.x;   // 16B unit id
    const int mat = gid >> 17;                        // 131072 units per matrix
    const int u = gid & 131071;
    const int chunk = u >> 10;                        // t*2 + p, 0..127
    const int b16 = u & 1023;                         // 16B unit within chunk
    const int tt = chunk >> 1, p = chunk & 1;
    const int r = b16 >> 3;                           // tile row 0..127
    const int k2 = (((b16 & 7) << 4) ^ ((r & 7) << 4));  // byte offset in row data
    const int k = k2 >> 1;                            // bf16 element 0..56 step 8
    const float* src = (mat ? Y : X) + (size_t)(tt * TILE + r) * D_DIM + p * 64 + k;
    float4 a = *(const float4*)src;
    float4 b = *(const float4*)(src + 4);
    u16x8 h = { f32_to_bf16(a.x), f32_to_bf16(a.y), f32_to_bf16(a.z), f32_to_bf16(a.w),
                f32_to_bf16(b.x), f32_to_bf16(b.y), f32_to_bf16(b.z), f32_to_bf16(b.w) };
    unsigned short* dst = (mat ? Yt : Xt) + (size_t)chunk * 8192 + (size_t)b16 * 8;
    *(u16x8*)dst = h;
}

// 128x128 output tile per block, 2 K=64 phases, global_load_lds staging.
// LDS rows are linear 128 B; bank conflicts broken by the pre-baked XOR swizzle
// (byte ^= (row&7)<<4), applied on the ds_read address.
// MFMA computes the TRANSPOSED tile (A=Y frag, B=X frag) so the 4 acc regs of each
// 16x16 tile are 4 consecutive output COLUMNS for a fixed row -> direct dwordx4 stores.
__global__ __launch_bounds__(256, 4) void rbf_main(const unsigned short* __restrict__ Xt,
                                                   const unsigned short* __restrict__ Yt,
                                                   const float* __restrict__ sigma,
                                                   const float* __restrict__ nrm,
                                                   float* __restrict__ out) {
    __shared__ unsigned short Xs[8192];   // 16 KB (one phase)
    __shared__ unsigned short Ys[8192];   // 16 KB
    __shared__ float x2s[TILE];
    __shared__ float y2s[TILE];

    const int t = threadIdx.x;

    // XCD swizzle: flat%8 -> XCD; each XCD's 512 blocks cover 8 row-tiles x all
    // 64 col-tiles -> reads 256KB X + 2MB Y, resident in its 4 MiB L2.
    const int flat = blockIdx.y * 64 + blockIdx.x;
    const int nf = (flat & 7) * 512 + (flat >> 3);
    const int tyi = nf >> 6;              // X row tile
    const int txi = nf & 63;              // Y row tile (out col tile)
    const int row0 = tyi * TILE;
    const int col0 = txi * TILE;

    if (t < 128) x2s[t] = nrm[row0 + t];
    else         y2s[t - 128] = nrm[NROW + col0 + (t - 128)];

    const int w = t >> 6, ln = t & 63;
    const int quad = ln >> 4, l16 = ln & 15;
    const int wr = (w >> 1) * 64;   // X-dim half of the tile for this wave
    const int wc = (w & 1) * 64;    // Y-dim half
    const int xorv = (l16 & 7) << 4;

    f32x4 acc[4][4] = {};   // [ti = X-dim 16-frag][tj = Y-dim 16-frag]

    #pragma unroll
    for (int p = 0; p < 2; ++p) {
        const char* gx = (const char*)Xt + ((size_t)(tyi * 2 + p) << 14);
        const char* gy = (const char*)Yt + ((size_t)(txi * 2 + p) << 14);
        #pragma unroll
        for (int i = 0; i < 4; ++i) {
            const int off = ((w * 4 + i) * 64 + ln) * 16;   // per-lane global byte
            const int loff = (w * 4 + i) * 1024;            // wave-uniform LDS byte
            __builtin_amdgcn_global_load_lds(
                (const __attribute__((address_space(1))) unsigned int*)(gx + off),
                (__attribute__((address_space(3))) unsigned int*)((char*)Xs + loff),
                16, 0, 0);
            __builtin_amdgcn_global_load_lds(
                (const __attribute__((address_space(1))) unsigned int*)(gy + off),
                (__attribute__((address_space(3))) unsigned int*)((char*)Ys + loff),
                16, 0, 0);
        }
        asm volatile("s_waitcnt vmcnt(0)" ::: "memory");
        __syncthreads();

        #pragma unroll
        for (int ks = 0; ks < 2; ++ks) {
            const int kb = (((ks << 6) | (quad << 4)) ^ xorv);  // swizzled k-byte
            bf16x8 ax[4], by[4];
            #pragma unroll
            for (int ti = 0; ti < 4; ++ti)
                ax[ti] = *(const bf16x8*)((const char*)Xs + (wr + ti * 16 + l16) * 128 + kb);
            #pragma unroll
            for (int tj = 0; tj < 4; ++tj)
                by[tj] = *(const bf16x8*)((const char*)Ys + (wc + tj * 16 + l16) * 128 + kb);
            #pragma unroll
            for (int ti = 0; ti < 4; ++ti)
                #pragma unroll
                for (int tj = 0; tj < 4; ++tj)
                    // A = Y frag (rows = out cols), B = X frag (cols = out rows)
                    acc[ti][tj] = __builtin_amdgcn_mfma_f32_16x16x32_bf16(by[tj], ax[ti], acc[ti][tj], 0, 0, 0);
        }
        if (p == 0) __syncthreads();   // phase-0 reads done before phase-1 restage
    }

    const float s2 = sigma[0] * sigma[0] + 1e-9f;
    const float cexp = -1.4426950408889634f / s2;   // exp(-d/s2) = exp2(d * cexp)

    // D layout: col(n) = l16 -> X row; row(m) = quad*4 + r -> Y row (out column).
    float x2r[4];
    #pragma unroll
    for (int ti = 0; ti < 4; ++ti) x2r[ti] = x2s[wr + ti * 16 + l16];

    #pragma unroll
    for (int tj = 0; tj < 4; ++tj) {
        f32x4 y2v = *(const f32x4*)(&y2s[wc + tj * 16 + quad * 4]);
        size_t gcol = (size_t)(col0 + wc + tj * 16 + quad * 4);
        #pragma unroll
        for (int ti = 0; ti < 4; ++ti) {
            f32x4 v;
            #pragma unroll
            for (int r = 0; r < 4; ++r) {
                float d = x2r[ti] + y2v[r] - 2.0f * acc[ti][tj][r];
                v[r] = __builtin_amdgcn_exp2f(d * cexp);
            }
            size_t grow = (size_t)(row0 + wr + ti * 16 + l16);
            // plain store: let L2 merge the two 64B halves of each 128B line
            *(f32x4*)(out + grow * OUT_LD + gcol) = v;
        }
    }
}

extern "C" void kernel_launch(void* const* d_in, const int* in_sizes, int n_in,
                              void* d_out, int out_size, void* d_ws, size_t ws_size,
                              hipStream_t stream) {
    const float* X = (const float*)d_in[0];
    const float* Y = (const float*)d_in[1];
    const float* sigma = (const float*)d_in[2];
    float* nrm = (float*)d_ws;                                   // 16384 f32 = 64 KB
    unsigned short* Xt = (unsigned short*)((char*)d_ws + 65536); // 2 MB bf16 tiles
    unsigned short* Yt = Xt + (size_t)128 * 8192;                // 2 MB bf16 tiles
    float* out = (float*)d_out;

    rbf_norms<<<(NROW + MROW) / 4, 256, 0, stream>>>(X, Y, nrm);
    rbf_pack<<<1024, 256, 0, stream>>>(X, Y, Xt, Yt);
    rbf_main<<<dim3(MROW / TILE, NROW / TILE), 256, 0, stream>>>(Xt, Yt, sigma, nrm, out);
}